// Round 5
// baseline (424.568 us; speedup 1.0000x reference)
//
#include <hip/hip_runtime.h>
#include <math.h>

#define S_LEN 2048
#define D_KV  64
#define BQ    128   // q rows per block: 4 q-waves x 32 (x2 split-K groups)
#define BK    64
#define KHALF 1024
#define NT    (KHALF / BK)   // 16 iterations per split-K group

typedef __attribute__((ext_vector_type(8)))  short bh8;   // 8 bf16 (MFMA A/B frag)
typedef __attribute__((ext_vector_type(4)))  float fx4;
typedef __attribute__((ext_vector_type(16))) float fx16;  // 32x32 MFMA C/D frag
typedef __attribute__((ext_vector_type(4)))  unsigned int u32x4;
typedef __attribute__((ext_vector_type(2)))  unsigned int u32x2;

__device__ __forceinline__ unsigned cvt2(float a, float b) {
    unsigned r;
    asm("v_cvt_pk_bf16_f32 %0, %1, %2" : "=v"(r) : "v"(a), "v"(b));
    return r;
}
// v_permlane32_swap_b32 d, s: exchanges d lanes 32-63 with s lanes 0-31.
__device__ __forceinline__ void swap32(unsigned &d, unsigned &s) {
    asm("v_permlane32_swap_b32 %0, %1" : "+v"(d), "+v"(s));
}
__device__ __forceinline__ float exp2_fast(float x) {   // native 2^x
    float r;
    asm("v_exp_f32 %0, %1" : "=v"(r) : "v"(x));
    return r;
}
// row-major [row][64 bf16] tile, bank swizzle; same map on write and read
__device__ __forceinline__ int swz(int row, int byteoff) {
    return (row << 7) + (byteoff ^ ((row & 7) << 4));
}

__global__ __launch_bounds__(512, 4)
void attn_fwd(const float* __restrict__ Qg, const float* __restrict__ Kg,
              const float* __restrict__ Vg, const float* __restrict__ Mg,
              float* __restrict__ Og)
{
    // per (kg,buf): K 8KB + V^T 8KB = 16KB; 2 kg x 2 buf = 64 KB total.
    // Epilogue reuses [0, 36864) as the split-K combine scratch.
    __shared__ __align__(16) char smem[65536];

    const int tid  = threadIdx.x;
    const int lane = tid & 63;
    const int wave = tid >> 6;   // 0..7
    const int qw   = wave & 3;   // q-wave within block
    const int kg   = wave >> 2;  // split-K group: 0 -> keys [0,1024), 1 -> [1024,2048)
    const int lq   = lane & 31;  // q row (MFMA col)
    const int hf   = lane >> 5;  // half-wave (k-slice selector)

    // XCD-aware bijective swizzle: 512 blocks, 64 contiguous per XCD
    const int flat = blockIdx.x + (int)gridDim.x * blockIdx.y;   // 0..511
    const int nsw  = (flat & 7) * 64 + (flat >> 3);
    const int qt = nsw & 15;
    const int bh = nsw >> 4;
    const int b  = bh >> 4;

    const int qbase = qt * BQ + qw * 32;

    const float* Kp = Kg + ((size_t)bh * S_LEN + kg * KHALF) * D_KV;
    const float* Vp = Vg + ((size_t)bh * S_LEN + kg * KHALF) * D_KV;
    const float* Qp = Qg + ((size_t)bh * S_LEN + qbase) * D_KV;
    const float* mrow = Mg + (size_t)b * S_LEN * S_LEN
                      + (size_t)(qbase + lq) * S_LEN + kg * KHALF + hf * 4;

    // ---- Q as 32x32x16 B-frags; scale (1/8)*log2(e): exp() -> native exp2 ----
    const float QS = 0.125f * 1.44269504f;
    bh8 qf[4];
#pragma unroll
    for (int ks = 0; ks < 4; ++ks) {
        const float* src = Qp + lq * D_KV + ks * 16 + hf * 8;
        fx4 a0 = *(const fx4*)src;
        fx4 a1 = *(const fx4*)(src + 4);
        u32x4 q4 = { cvt2(a0[0] * QS, a0[1] * QS),
                     cvt2(a0[2] * QS, a0[3] * QS),
                     cvt2(a1[0] * QS, a1[1] * QS),
                     cvt2(a1[2] * QS, a1[3] * QS) };
        qf[ks] = __builtin_bit_cast(bh8, q4);
    }

    // ---- staging maps: the 256 threads of each kg group stage its tile ----
    const int stid  = tid & 255;
    const int krow  = stid >> 2;           // K: one row per 4 threads
    const int kcolf = (stid & 3) << 2;     // float col base; +16 per i
    const int vd0   = (stid >> 4) << 2;    // V: 4x4 transpose block
    const int vk0   = (stid & 15) << 2;

    char* lbase = smem + kg * 32768;

    fx4 kreg[4], vreg[4];                  // T14 prefetch registers
    auto issue = [&](int t) {
        const int k0 = t * BK;
#pragma unroll
        for (int i = 0; i < 4; ++i)
            kreg[i] = *(const fx4*)(Kp + (size_t)(k0 + krow) * D_KV + kcolf + 16 * i);
#pragma unroll
        for (int i = 0; i < 4; ++i)
            vreg[i] = *(const fx4*)(Vp + (size_t)(k0 + vk0 + i) * D_KV + vd0);
    };
    auto store_kv = [&](int buf) {
        char* kbW = lbase + buf * 16384;
        char* vbW = kbW + 8192;
#pragma unroll
        for (int i = 0; i < 4; ++i) {
            u32x2 w = { cvt2(kreg[i][0], kreg[i][1]),
                        cvt2(kreg[i][2], kreg[i][3]) };
            *(u32x2*)(kbW + swz(krow, (kcolf << 1) + 32 * i)) = w;
        }
#pragma unroll
        for (int i = 0; i < 4; ++i) {
            u32x2 w = { cvt2(vreg[0][i], vreg[1][i]),
                        cvt2(vreg[2][i], vreg[3][i]) };
            *(u32x2*)(vbW + swz(vd0 + i, vk0 << 1)) = w;
        }
    };

    fx16 o0 = {}, o1 = {};                 // O^T[d][q=lq], d-blocks 0/1
    float lsum = 0.f;

    // ---- prologue: tile0 -> buf0; tile1 in regs; publish, no vmcnt drain ----
    issue(0);
    store_kv(0);
    issue(1);
    asm volatile("s_waitcnt lgkmcnt(0)" ::: "memory");
    __builtin_amdgcn_s_barrier();

#pragma unroll 1
    for (int t = 0; t < NT; ++t) {
        char* kbR = lbase + (t & 1) * 16384;
        char* vbR = kbR + 8192;
        const int mc = t * BK;

        // mask loads rb=0 (no drain at barriers: stay in flight under compute)
        fx4 mv0[4];
#pragma unroll
        for (int m = 0; m < 4; ++m)
            mv0[m] = *(const fx4*)(mrow + mc + m * 8);

        // stage tile t+1 into the other buffer (overlaps this tile's compute)
        if (t + 1 < NT) store_kv((t + 1) & 1);

        // ---- QK^T swapped: st = mfma(K, Q) = S^T[key][q=lq] ----
        // key(reg r, rb) = rb*32 + 8*(r>>2) + 4*hf + (r&3)
        fx16 st0 = {}, st1 = {};
        __builtin_amdgcn_s_setprio(1);
#pragma unroll
        for (int ks = 0; ks < 4; ++ks) {
            bh8 k0 = *(const bh8*)(kbR + swz(lq,      ks * 32 + hf * 16));
            bh8 k1 = *(const bh8*)(kbR + swz(32 + lq, ks * 32 + hf * 16));
            st0 = __builtin_amdgcn_mfma_f32_32x32x16_bf16(k0, qf[ks], st0, 0, 0, 0);
            st1 = __builtin_amdgcn_mfma_f32_32x32x16_bf16(k1, qf[ks], st1, 0, 0, 0);
        }
        __builtin_amdgcn_s_setprio(0);

        // mask loads rb=1, then next-next tile prefetch (covered to next iter)
        fx4 mv1[4];
#pragma unroll
        for (int m = 0; m < 4; ++m)
            mv1[m] = *(const fx4*)(mrow + mc + 32 + m * 8);
        if (t + 2 < NT) issue(t + 2);

        unsigned pkw[16];

        // ---- softmax rb=0: mask * keep-positive * exp2 (fixed max 0) ----
#pragma unroll
        for (int m = 0; m < 4; ++m) {
            float tm0 = st0[4*m+0] * mv0[m][0];
            float tm1 = st0[4*m+1] * mv0[m][1];
            float tm2 = st0[4*m+2] * mv0[m][2];
            float tm3 = st0[4*m+3] * mv0[m][3];
            float p0 = tm0 > 0.f ? exp2_fast(tm0) : 0.f;
            float p1 = tm1 > 0.f ? exp2_fast(tm1) : 0.f;
            float p2 = tm2 > 0.f ? exp2_fast(tm2) : 0.f;
            float p3 = tm3 > 0.f ? exp2_fast(tm3) : 0.f;
            lsum += (p0 + p1) + (p2 + p3);
            pkw[m*2+0] = cvt2(p0, p1);
            pkw[m*2+1] = cvt2(p2, p3);
        }

        // ---- PV keys 0..31 (B-frag via permlane32_swap, round-4-verified) ----
        __builtin_amdgcn_s_setprio(1);
#pragma unroll
        for (int vp = 0; vp < 2; ++vp) {
            unsigned w0 = pkw[vp*4+0], w1 = pkw[vp*4+1];
            unsigned w2 = pkw[vp*4+2], w3 = pkw[vp*4+3];
            swap32(w0, w2); swap32(w1, w3);
            u32x4 pq = { w0, w1, w2, w3 };
            bh8 pb = __builtin_bit_cast(bh8, pq);
            bh8 v0 = *(const bh8*)(vbR + swz(lq,      vp * 32 + hf * 16));
            bh8 v1 = *(const bh8*)(vbR + swz(32 + lq, vp * 32 + hf * 16));
            o0 = __builtin_amdgcn_mfma_f32_32x32x16_bf16(v0, pb, o0, 0, 0, 0);
            o1 = __builtin_amdgcn_mfma_f32_32x32x16_bf16(v1, pb, o1, 0, 0, 0);
        }
        __builtin_amdgcn_s_setprio(0);

        // ---- softmax rb=1 ----
#pragma unroll
        for (int m = 0; m < 4; ++m) {
            float tm0 = st1[4*m+0] * mv1[m][0];
            float tm1 = st1[4*m+1] * mv1[m][1];
            float tm2 = st1[4*m+2] * mv1[m][2];
            float tm3 = st1[4*m+3] * mv1[m][3];
            float p0 = tm0 > 0.f ? exp2_fast(tm0) : 0.f;
            float p1 = tm1 > 0.f ? exp2_fast(tm1) : 0.f;
            float p2 = tm2 > 0.f ? exp2_fast(tm2) : 0.f;
            float p3 = tm3 > 0.f ? exp2_fast(tm3) : 0.f;
            lsum += (p0 + p1) + (p2 + p3);
            pkw[8 + m*2+0] = cvt2(p0, p1);
            pkw[8 + m*2+1] = cvt2(p2, p3);
        }

        // ---- PV keys 32..63 ----
        __builtin_amdgcn_s_setprio(1);
#pragma unroll
        for (int vp = 2; vp < 4; ++vp) {
            unsigned w0 = pkw[vp*4+0], w1 = pkw[vp*4+1];
            unsigned w2 = pkw[vp*4+2], w3 = pkw[vp*4+3];
            swap32(w0, w2); swap32(w1, w3);
            u32x4 pq = { w0, w1, w2, w3 };
            bh8 pb = __builtin_bit_cast(bh8, pq);
            bh8 v0 = *(const bh8*)(vbR + swz(lq,      vp * 32 + hf * 16));
            bh8 v1 = *(const bh8*)(vbR + swz(32 + lq, vp * 32 + hf * 16));
            o0 = __builtin_amdgcn_mfma_f32_32x32x16_bf16(v0, pb, o0, 0, 0, 0);
            o1 = __builtin_amdgcn_mfma_f32_32x32x16_bf16(v1, pb, o1, 0, 0, 0);
        }
        __builtin_amdgcn_s_setprio(0);

        // publish LDS writes only (ds ops); global prefetch stays in flight
        asm volatile("s_waitcnt lgkmcnt(0)" ::: "memory");
        __builtin_amdgcn_s_barrier();
    }

    // ---- per-group row sum across half-waves (same q, complementary keys) ----
    lsum += __shfl_xor(lsum, 32);

    // ---- split-K combine: fixed-max softmax => partials add linearly ----
    float* scr = (float*)smem;             // 256 slots x 36 floats = 36864 B
    const int slot = qw * 64 + lane;
    if (kg) {
        float* d = scr + slot * 36;
#pragma unroll
        for (int i = 0; i < 4; ++i) {
            fx4 c0 = { o0[4*i+0], o0[4*i+1], o0[4*i+2], o0[4*i+3] };
            *(fx4*)(d + 4 * i) = c0;
            fx4 c1 = { o1[4*i+0], o1[4*i+1], o1[4*i+2], o1[4*i+3] };
            *(fx4*)(d + 16 + 4 * i) = c1;
        }
        d[32] = lsum;
    }
    __syncthreads();
    if (!kg) {
        const float* s = scr + slot * 36;
#pragma unroll
        for (int i = 0; i < 4; ++i) {
            fx4 c0 = *(const fx4*)(s + 4 * i);
            o0[4*i+0] += c0[0]; o0[4*i+1] += c0[1];
            o0[4*i+2] += c0[2]; o0[4*i+3] += c0[3];
            fx4 c1 = *(const fx4*)(s + 16 + 4 * i);
            o1[4*i+0] += c1[0]; o1[4*i+1] += c1[1];
            o1[4*i+2] += c1[2]; o1[4*i+3] += c1[3];
        }
        lsum += s[32];
        const float inv = 1.0f / lsum;

        // epilogue: O[q][d], d = db*32 + 8m + 4*hf + j
        float* orow = Og + ((size_t)bh * S_LEN + qbase + lq) * D_KV;
#pragma unroll
        for (int m = 0; m < 4; ++m) {
            fx4 r0 = { o0[4*m+0]*inv, o0[4*m+1]*inv, o0[4*m+2]*inv, o0[4*m+3]*inv };
            *(fx4*)(orow + m * 8 + hf * 4) = r0;
            fx4 r1 = { o1[4*m+0]*inv, o1[4*m+1]*inv, o1[4*m+2]*inv, o1[4*m+3]*inv };
            *(fx4*)(orow + 32 + m * 8 + hf * 4) = r1;
        }
    }
}

extern "C" void kernel_launch(void* const* d_in, const int* in_sizes, int n_in,
                              void* d_out, int out_size, void* d_ws, size_t ws_size,
                              hipStream_t stream) {
    const float* Q = (const float*)d_in[0];
    const float* K = (const float*)d_in[1];
    const float* V = (const float*)d_in[2];
    const float* M = (const float*)d_in[3];
    float*       O = (float*)d_out;
    dim3 grid(S_LEN / BQ, 32);   // 16 q-tiles x (B*H)=32
    attn_fwd<<<grid, 512, 0, stream>>>(Q, K, V, M, O);
}

// Round 6
// 194.682 us; speedup vs baseline: 2.1808x; 2.1808x over previous
//
#include <hip/hip_runtime.h>
#include <math.h>

#define S_LEN 2048
#define D_KV  64
#define BQ    128   // q rows per block: 4 waves x 32
#define BK    64
#define NT    (S_LEN / BK)   // 32 k-tiles

typedef __attribute__((ext_vector_type(8)))  short bh8;   // 8 bf16 (MFMA A/B frag)
typedef __attribute__((ext_vector_type(4)))  float fx4;
typedef __attribute__((ext_vector_type(16))) float fx16;  // 32x32 MFMA C/D frag
typedef __attribute__((ext_vector_type(4)))  unsigned int u32x4;
typedef __attribute__((ext_vector_type(2)))  unsigned int u32x2;

__device__ __forceinline__ unsigned cvt2(float a, float b) {
    unsigned r;
    asm("v_cvt_pk_bf16_f32 %0, %1, %2" : "=v"(r) : "v"(a), "v"(b));
    return r;
}
// v_permlane32_swap_b32 d, s: exchanges d lanes 32-63 with s lanes 0-31.
__device__ __forceinline__ void swap32(unsigned &d, unsigned &s) {
    asm("v_permlane32_swap_b32 %0, %1" : "+v"(d), "+v"(s));
}
__device__ __forceinline__ float exp2_fast(float x) {   // native 2^x
    float r;
    asm("v_exp_f32 %0, %1" : "=v"(r) : "v"(x));
    return r;
}
// row-major [row][64 bf16] tile, bank swizzle; same map on write and read
__device__ __forceinline__ int swz(int row, int byteoff) {
    return (row << 7) + (byteoff ^ ((row & 7) << 4));
}

// ---- pre-pass: fp32 {0,1} mask -> bitmask, layout [b][kt64][qrow] u64 ----
__global__ __launch_bounds__(256)
void pack_mask(const float* __restrict__ M, unsigned long long* __restrict__ BM)
{
    const size_t i = (size_t)blockIdx.x * 256 + threadIdx.x;  // elem index
    const float v = M[i];
    const unsigned long long bits = __ballot(v > 0.5f);
    if ((threadIdx.x & 63) == 0) {
        const size_t g = i >> 6;               // global u64 index (row-major)
        const int col64 = (int)(g & 31);       // k-tile (64 cols each)
        const int row   = (int)((g >> 5) & 2047);
        const int b     = (int)(g >> 16);
        BM[((size_t)b * 32 + col64) * 2048 + row] = bits;
    }
}

__global__ __launch_bounds__(256, 3)
void attn_fwd(const float* __restrict__ Qg, const float* __restrict__ Kg,
              const float* __restrict__ Vg,
              const unsigned long long* __restrict__ BMg,
              float* __restrict__ Og)
{
    __shared__ __align__(16) char smem[16384];
    short* kb = (short*)smem;           // K  [64 keys][64 d] bf16, swizzled
    short* vb = (short*)(smem + 8192);  // V^T[64 d][64 keys] bf16, swizzled

    const int tid  = threadIdx.x;
    const int lane = tid & 63;
    const int wave = tid >> 6;    // 0..3
    const int lq   = lane & 31;   // q row within wave tile (MFMA col)
    const int hf   = lane >> 5;   // half-wave (k-slice selector)

    // XCD-aware bijective swizzle: 512 blocks, 64 contiguous per XCD
    const int flat = blockIdx.x + (int)gridDim.x * blockIdx.y;   // 0..511
    const int nsw  = (flat & 7) * 64 + (flat >> 3);
    const int qt = nsw & 15;
    const int bh = nsw >> 4;
    const int b  = bh >> 4;

    const int qbase = qt * BQ + wave * 32;

    const float* Kp = Kg + (size_t)bh * S_LEN * D_KV;
    const float* Vp = Vg + (size_t)bh * S_LEN * D_KV;
    const float* Qp = Qg + ((size_t)bh * S_LEN + qbase) * D_KV;
    // bitmask row pointer: [b][t][qrow]; per-iter stride 2048 u64
    const unsigned long long* BMp = BMg + (size_t)b * 32 * 2048 + qbase + lq;

    // ---- Q as 32x32x16 B-frags; scale (1/8)*log2(e): exp() -> native exp2 ----
    const float QS = 0.125f * 1.44269504f;
    bh8 qf[4];
#pragma unroll
    for (int ks = 0; ks < 4; ++ks) {
        const float* src = Qp + lq * D_KV + ks * 16 + hf * 8;
        fx4 a0 = *(const fx4*)src;
        fx4 a1 = *(const fx4*)(src + 4);
        u32x4 q4 = { cvt2(a0[0] * QS, a0[1] * QS),
                     cvt2(a0[2] * QS, a0[3] * QS),
                     cvt2(a1[0] * QS, a1[1] * QS),
                     cvt2(a1[2] * QS, a1[3] * QS) };
        qf[ks] = __builtin_bit_cast(bh8, q4);
    }

    // ---- staging maps (all 256 threads stage both K and V) ----
    const int krow = tid >> 2;           // K: one row per 4 threads
    const int kcol = (tid & 3) << 2;     // float col base; +16 per i
    const int vd0  = (tid >> 4) << 2;    // V: 4x4 transpose block
    const int vk0  = (tid & 15) << 2;

    fx16 o0 = {}, o1 = {};               // O^T[d][q=lq], d-blocks 0/1
    float lsum = 0.f;
    fx4 kreg[4], vreg[4];                // T14 prefetch registers

    auto issue = [&](int kt) {
#pragma unroll
        for (int i = 0; i < 4; ++i)
            kreg[i] = *(const fx4*)(Kp + (size_t)(kt + krow) * D_KV + kcol + 16 * i);
#pragma unroll
        for (int i = 0; i < 4; ++i)
            vreg[i] = *(const fx4*)(Vp + (size_t)(kt + vk0 + i) * D_KV + vd0);
    };

    issue(0);   // prologue prefetch

#pragma unroll 1
    for (int t = 0; t < NT; ++t) {
        // ---- bitmask for this tile: ONE 8B load per lane (was 128B fp32) ----
        const unsigned long long bm = BMp[(size_t)t * 2048];

        // ---- drain prefetched K/V regs -> swizzled LDS; publish (lgkm only,
        //      no vmcnt drain: raw barrier, not __syncthreads) ----
#pragma unroll
        for (int i = 0; i < 4; ++i) {
            u32x2 w = { cvt2(kreg[i][0], kreg[i][1]),
                        cvt2(kreg[i][2], kreg[i][3]) };
            *(u32x2*)((char*)kb + swz(krow, (kcol << 1) + 32 * i)) = w;
        }
#pragma unroll
        for (int i = 0; i < 4; ++i) {
            u32x2 w = { cvt2(vreg[0][i], vreg[1][i]),
                        cvt2(vreg[2][i], vreg[3][i]) };
            *(u32x2*)((char*)vb + swz(vd0 + i, vk0 << 1)) = w;
        }
        asm volatile("s_waitcnt lgkmcnt(0)" ::: "memory");
        __builtin_amdgcn_s_barrier();

        // ---- prefetch next tile; stays in flight across the whole compute ----
        if (t + 1 < NT) issue((t + 1) * BK);

        // ---- QK^T swapped: st = mfma(K, Q) = S^T[key][q=lq] ----
        // key(reg r, rb) = rb*32 + 8*(r>>2) + 4*hf + (r&3)
        fx16 st0 = {}, st1 = {};
        __builtin_amdgcn_s_setprio(1);
#pragma unroll
        for (int ks = 0; ks < 4; ++ks) {
            bh8 k0 = *(const bh8*)((char*)kb + swz(lq,      ks * 32 + hf * 16));
            bh8 k1 = *(const bh8*)((char*)kb + swz(32 + lq, ks * 32 + hf * 16));
            st0 = __builtin_amdgcn_mfma_f32_32x32x16_bf16(k0, qf[ks], st0, 0, 0, 0);
            st1 = __builtin_amdgcn_mfma_f32_32x32x16_bf16(k1, qf[ks], st1, 0, 0, 0);
        }
        __builtin_amdgcn_s_setprio(0);

        // per-half-wave aligned bit windows: bit(8m+j) of s0/s1 = key rb*32+8m+4hf+j
        const unsigned s0 = ((unsigned)bm) >> (hf * 4);
        const unsigned s1 = ((unsigned)(bm >> 32)) >> (hf * 4);

        unsigned pkw[16];

        // ---- softmax rb=0: keep iff (bit && s>0); p = exp2(s*log2e) ----
#pragma unroll
        for (int m = 0; m < 4; ++m) {
            const unsigned bb = s0 >> (8 * m);
            float tm0 = st0[4*m+0], tm1 = st0[4*m+1];
            float tm2 = st0[4*m+2], tm3 = st0[4*m+3];
            float p0 = ((bb      & 1) && tm0 > 0.f) ? exp2_fast(tm0) : 0.f;
            float p1 = ((bb >> 1 & 1) && tm1 > 0.f) ? exp2_fast(tm1) : 0.f;
            float p2 = ((bb >> 2 & 1) && tm2 > 0.f) ? exp2_fast(tm2) : 0.f;
            float p3 = ((bb >> 3 & 1) && tm3 > 0.f) ? exp2_fast(tm3) : 0.f;
            lsum += (p0 + p1) + (p2 + p3);
            pkw[m*2+0] = cvt2(p0, p1);
            pkw[m*2+1] = cvt2(p2, p3);
        }

        // ---- PV keys 0..31 (B-frag via permlane32_swap, round-4-verified) ----
        __builtin_amdgcn_s_setprio(1);
#pragma unroll
        for (int vp = 0; vp < 2; ++vp) {
            unsigned w0 = pkw[vp*4+0], w1 = pkw[vp*4+1];
            unsigned w2 = pkw[vp*4+2], w3 = pkw[vp*4+3];
            swap32(w0, w2); swap32(w1, w3);
            u32x4 pq = { w0, w1, w2, w3 };
            bh8 pb = __builtin_bit_cast(bh8, pq);
            bh8 v0 = *(const bh8*)((char*)vb + swz(lq,      vp * 32 + hf * 16));
            bh8 v1 = *(const bh8*)((char*)vb + swz(32 + lq, vp * 32 + hf * 16));
            o0 = __builtin_amdgcn_mfma_f32_32x32x16_bf16(v0, pb, o0, 0, 0, 0);
            o1 = __builtin_amdgcn_mfma_f32_32x32x16_bf16(v1, pb, o1, 0, 0, 0);
        }
        __builtin_amdgcn_s_setprio(0);

        // ---- softmax rb=1 ----
#pragma unroll
        for (int m = 0; m < 4; ++m) {
            const unsigned bb = s1 >> (8 * m);
            float tm0 = st1[4*m+0], tm1 = st1[4*m+1];
            float tm2 = st1[4*m+2], tm3 = st1[4*m+3];
            float p0 = ((bb      & 1) && tm0 > 0.f) ? exp2_fast(tm0) : 0.f;
            float p1 = ((bb >> 1 & 1) && tm1 > 0.f) ? exp2_fast(tm1) : 0.f;
            float p2 = ((bb >> 2 & 1) && tm2 > 0.f) ? exp2_fast(tm2) : 0.f;
            float p3 = ((bb >> 3 & 1) && tm3 > 0.f) ? exp2_fast(tm3) : 0.f;
            lsum += (p0 + p1) + (p2 + p3);
            pkw[8 + m*2+0] = cvt2(p0, p1);
            pkw[8 + m*2+1] = cvt2(p2, p3);
        }

        // ---- PV keys 32..63 ----
        __builtin_amdgcn_s_setprio(1);
#pragma unroll
        for (int vp = 2; vp < 4; ++vp) {
            unsigned w0 = pkw[vp*4+0], w1 = pkw[vp*4+1];
            unsigned w2 = pkw[vp*4+2], w3 = pkw[vp*4+3];
            swap32(w0, w2); swap32(w1, w3);
            u32x4 pq = { w0, w1, w2, w3 };
            bh8 pb = __builtin_bit_cast(bh8, pq);
            bh8 v0 = *(const bh8*)((char*)vb + swz(lq,      vp * 32 + hf * 16));
            bh8 v1 = *(const bh8*)((char*)vb + swz(32 + lq, vp * 32 + hf * 16));
            o0 = __builtin_amdgcn_mfma_f32_32x32x16_bf16(v0, pb, o0, 0, 0, 0);
            o1 = __builtin_amdgcn_mfma_f32_32x32x16_bf16(v1, pb, o1, 0, 0, 0);
        }
        __builtin_amdgcn_s_setprio(0);

        // all LDS reads of this tile retired (compiler waits before MFMA use);
        // barrier alone orders waves — no vmcnt drain here either.
        __builtin_amdgcn_s_barrier();
    }

    // ---- row sum: lane l and l^32 hold the same q, complementary keys ----
    lsum += __shfl_xor(lsum, 32);
    const float inv = 1.0f / lsum;

    // ---- epilogue: O[q][d], d = db*32 + 8m + 4*hf + j ----
    float* orow = Og + ((size_t)bh * S_LEN + qbase + lq) * D_KV;
#pragma unroll
    for (int m = 0; m < 4; ++m) {
        fx4 r0 = { o0[4*m+0]*inv, o0[4*m+1]*inv, o0[4*m+2]*inv, o0[4*m+3]*inv };
        *(fx4*)(orow + m * 8 + hf * 4) = r0;
        fx4 r1 = { o1[4*m+0]*inv, o1[4*m+1]*inv, o1[4*m+2]*inv, o1[4*m+3]*inv };
        *(fx4*)(orow + 32 + m * 8 + hf * 4) = r1;
    }
}

extern "C" void kernel_launch(void* const* d_in, const int* in_sizes, int n_in,
                              void* d_out, int out_size, void* d_ws, size_t ws_size,
                              hipStream_t stream) {
    const float* Q = (const float*)d_in[0];
    const float* K = (const float*)d_in[1];
    const float* V = (const float*)d_in[2];
    const float* M = (const float*)d_in[3];
    float*       O = (float*)d_out;
    unsigned long long* BM = (unsigned long long*)d_ws;   // 1 MiB bitmask

    // pack mask: 2*2048*2048 elems / 256 = 32768 blocks
    pack_mask<<<dim3(32768), 256, 0, stream>>>(M, BM);

    dim3 grid(S_LEN / BQ, 32);   // 16 q-tiles x (B*H)=32
    attn_fwd<<<grid, 256, 0, stream>>>(Q, K, V, BM, O);
}